// Round 5
// baseline (293.440 us; speedup 1.0000x reference)
//
#include <hip/hip_runtime.h>
#include <stdint.h>

// GatingLayer: logits = x[16384,3072] . W[8,3072]^T + b[8]; softmax(8);
// top-2 (lowest-index tie-break); softmax over the selected 2.
// d_out = values (fp32 x 32768) ++ indices-as-float (x 32768).
//
// R5 design: small per-wave tile, big grid (occupancy fixes latency).
//  - 16 tokens/wave (2 passes x 8), 64 tokens/block, grid (256,8) = 2048
//    blocks = 8 blocks/CU; __launch_bounds__(256,4) caps VGPR at 128.
//  - x: global -> registers, 2-stage double buffer (precise per-reg vmcnt).
//  - W chunk in LDS (12 KB), broadcast ds_read_b128 (lgkm domain).
//  - lane = sl*8+tg: tg = token-in-group, sl = 4-float d-slice; slices
//    reduced with a 3-round shfl_xor butterfly at the end.
//  - Split-D partials to d_ws (plain stores, no atomics), summed in topk.

#define NTOK   16384
#define DMODEL 3072
#define NEXP   8
#define NDB    8                  // d-split across blockIdx.y
#define DCH    (DMODEL / NDB)     // 384 d per block
#define DS     32                 // d per stage
#define NST    (DCH / DS)         // 12 stages
#define TPB    256                // 4 waves
#define TOKB   64                 // tokens per block (16 per wave)

__global__ __launch_bounds__(TPB, 4) void gate_logits_kernel(
    const float* __restrict__ x, const float* __restrict__ W,
    float* __restrict__ part) {
  __shared__ float sw[NEXP * DCH];  // 12 KB: this block's W d-chunk

  const int tid = threadIdx.x;
  const int wv = tid >> 6;
  const int lane = tid & 63;
  const int sl = lane >> 3;       // d-slice [0,8)
  const int tg = lane & 7;        // token-in-group [0,8)
  const int tokBase = blockIdx.x * TOKB;
  const int dBase = blockIdx.y * DCH;

  // Stage W chunk into LDS once (768 float4 over 256 threads, 3 each).
  for (int f = tid; f < NEXP * DCH / 4; f += TPB) {
    const int e = f / (DCH / 4);
    const int j = f - e * (DCH / 4);
    *(float4*)&sw[e * DCH + j * 4] =
        *(const float4*)&W[e * DMODEL + dBase + j * 4];
  }
  __syncthreads();  // only block-wide barrier in the kernel

  // Lane's base pointer: token (tokBase + wv*16 + tg), slice sl.
  // Pass p (0/1) adds p*8 tokens; stage s adds s*DS floats.
  const float* b0 =
      x + (size_t)(tokBase + wv * 16 + tg) * DMODEL + dBase + sl * 4;

  float acc[2][NEXP];
#pragma unroll
  for (int p = 0; p < 2; ++p)
#pragma unroll
    for (int e = 0; e < NEXP; ++e) acc[p][e] = 0.f;

  float4 xa[2], xb[2];
  xa[0] = *(const float4*)(b0);
  xa[1] = *(const float4*)(b0 + 8 * DMODEL);

#pragma unroll 1
  for (int s = 0; s < NST; s += 2) {
    // Prefetch stage s+1 (register dbuf; compiler emits precise vmcnt).
    xb[0] = *(const float4*)(b0 + (s + 1) * DS);
    xb[1] = *(const float4*)(b0 + 8 * DMODEL + (s + 1) * DS);

    float4 w4[NEXP];
#pragma unroll
    for (int e = 0; e < NEXP; ++e)
      w4[e] = *(const float4*)&sw[e * DCH + s * DS + sl * 4];

#pragma unroll
    for (int p = 0; p < 2; ++p) {
      const float4 xv = xa[p];
#pragma unroll
      for (int e = 0; e < NEXP; ++e)
        acc[p][e] = fmaf(xv.x, w4[e].x,
                    fmaf(xv.y, w4[e].y,
                    fmaf(xv.z, w4[e].z,
                    fmaf(xv.w, w4[e].w, acc[p][e]))));
    }

    if (s + 2 < NST) {
      xa[0] = *(const float4*)(b0 + (s + 2) * DS);
      xa[1] = *(const float4*)(b0 + 8 * DMODEL + (s + 2) * DS);
    }

#pragma unroll
    for (int e = 0; e < NEXP; ++e)
      w4[e] = *(const float4*)&sw[e * DCH + (s + 1) * DS + sl * 4];

#pragma unroll
    for (int p = 0; p < 2; ++p) {
      const float4 xv = xb[p];
#pragma unroll
      for (int e = 0; e < NEXP; ++e)
        acc[p][e] = fmaf(xv.x, w4[e].x,
                    fmaf(xv.y, w4[e].y,
                    fmaf(xv.z, w4[e].z,
                    fmaf(xv.w, w4[e].w, acc[p][e]))));
    }
  }

  // Reduce over d-slices (lane bits 3..5 butterfly). After this every lane
  // holds the full sums for its tg (both token passes).
#pragma unroll
  for (int p = 0; p < 2; ++p)
#pragma unroll
    for (int e = 0; e < NEXP; ++e) {
      float v = acc[p][e];
      v += __shfl_xor(v, 8, 64);
      v += __shfl_xor(v, 16, 64);
      v += __shfl_xor(v, 32, 64);
      acc[p][e] = v;
    }

  // Store: lanes sl<4 write one float4 each: p = sl>>1, expert-half = sl&1.
  if (sl < 4) {
    const int p = sl >> 1;
    const int h = sl & 1;
    const int tok = tokBase + wv * 16 + p * 8 + tg;
    *(float4*)&part[((size_t)blockIdx.y * NTOK + tok) * NEXP + h * 4] =
        make_float4(acc[p][h * 4 + 0], acc[p][h * 4 + 1],
                    acc[p][h * 4 + 2], acc[p][h * 4 + 3]);
  }
}

// Phase 2: sum NDB partials + bias + softmax(8) + top-2 + renorm softmax(2).
__global__ __launch_bounds__(64) void gate_topk_kernel(
    const float* __restrict__ part, const float* __restrict__ bias,
    float* __restrict__ out) {
  const int t = blockIdx.x * 64 + threadIdx.x;
  if (t >= NTOK) return;

  float l[NEXP];
#pragma unroll
  for (int e = 0; e < NEXP; ++e) l[e] = bias[e];
#pragma unroll
  for (int p = 0; p < NDB; ++p) {
    const float* pp = &part[(size_t)p * NTOK * NEXP + (size_t)t * NEXP];
    const float4 a = *(const float4*)pp;
    const float4 b = *(const float4*)(pp + 4);
    l[0] += a.x; l[1] += a.y; l[2] += a.z; l[3] += a.w;
    l[4] += b.x; l[5] += b.y; l[6] += b.z; l[7] += b.w;
  }

  float m = l[0];
#pragma unroll
  for (int e = 1; e < NEXP; ++e) m = fmaxf(m, l[e]);

  float p8[NEXP];
  float ssum = 0.f;
#pragma unroll
  for (int e = 0; e < NEXP; ++e) {
    p8[e] = expf(l[e] - m);
    ssum += p8[e];
  }
  const float inv = 1.f / ssum;
#pragma unroll
  for (int e = 0; e < NEXP; ++e) p8[e] *= inv;

  // top-2, first-occurrence on ties (matches jax.lax.top_k stable order).
  int i1 = 0;
  float v1 = p8[0];
#pragma unroll
  for (int e = 1; e < NEXP; ++e) {
    if (p8[e] > v1) { v1 = p8[e]; i1 = e; }
  }
  int i2 = -1;
  float v2 = -1.f;
#pragma unroll
  for (int e = 0; e < NEXP; ++e) {
    if (e == i1) continue;
    if (p8[e] > v2) { v2 = p8[e]; i2 = e; }
  }

  const float e2 = expf(v2 - v1);  // v1 >= v2
  const float r = 1.f / (1.f + e2);

  out[(size_t)t * 2 + 0] = r;
  out[(size_t)t * 2 + 1] = e2 * r;
  out[2 * NTOK + (size_t)t * 2 + 0] = (float)i1;
  out[2 * NTOK + (size_t)t * 2 + 1] = (float)i2;
}

extern "C" void kernel_launch(void* const* d_in, const int* in_sizes, int n_in,
                              void* d_out, int out_size, void* d_ws,
                              size_t ws_size, hipStream_t stream) {
  const float* x = (const float*)d_in[0];
  const float* W = (const float*)d_in[1];
  const float* b = (const float*)d_in[2];
  float* out = (float*)d_out;
  float* part = (float*)d_ws;  // NDB * NTOK * NEXP fp32 = 4 MB, fully written

  dim3 grid1(NTOK / TOKB, NDB);
  gate_logits_kernel<<<grid1, TPB, 0, stream>>>(x, W, part);

  gate_topk_kernel<<<NTOK / 64, 64, 0, stream>>>(part, b, out);
}